// Round 7
// baseline (221.151 us; speedup 1.0000x reference)
//
#include <hip/hip_runtime.h>
#include <hip/hip_fp16.h>

#define NN 100000
#define NE 1600000
#define D  64

#define B1   1024        // hist/scatter blocks (4 per CU); edge mapping shared
#define BSH  8           // bin = dst >> 8  (256 nodes per bin)
#define BMSK 255
#define NB   391         // ceil(NN / 256)
#define PAD  400         // hist row stride (ints)
#define CAPS 4864        // LDS edge capacity per bin (mean 4092, sigma 64)

typedef __attribute__((ext_vector_type(8))) _Float16 f16x8;
typedef __attribute__((ext_vector_type(4))) float    f32x4;

// wave-0 helper: exclusive scan of bsum[0..NB) -> binoff_l[0..NB]
__device__ __forceinline__ void scan_bsum_wave0(const int* __restrict__ bsum,
                                                int* binoff_l, int t) {
    if (t < 64) {
        int base = t * 7;                    // 64*7 = 448 >= 392
        int loc[7]; int run = 0;
#pragma unroll
        for (int j = 0; j < 7; ++j) {
            int idx = base + j;
            int v = (idx < NB) ? bsum[idx] : 0;
            loc[j] = run; run += v;
        }
        int pre = run;
#pragma unroll
        for (int off = 1; off < 64; off <<= 1) {
            int u = __shfl_up(pre, off);
            if (t >= off) pre += u;
        }
        pre -= run;                          // exclusive over lanes
#pragma unroll
        for (int j = 0; j < 7; ++j) {
            int idx = base + j;
            if (idx <= NB) binoff_l[idx] = pre + loc[j];
        }
    }
}

// ---------- hist: per-block bin counts, block-major (coalesced) ----------
__global__ __launch_bounds__(256) void k_hist(const int* __restrict__ dst,
                                              int* __restrict__ hist) {
    __shared__ int h[NB];
    int t = threadIdx.x, blk = blockIdx.x;
    for (int i = t; i < NB; i += 256) h[i] = 0;
    __syncthreads();
    for (int e = blk * 256 + t; e < NE; e += B1 * 256)
        atomicAdd(&h[dst[e] >> BSH], 1);
    __syncthreads();
    for (int i = t; i < NB; i += 256) hist[blk * PAD + i] = h[i];
}

// ---------- scanT: per-bin exclusive scan over the 1024 block counts ----------
// 8 bins per block; hist updated in-place; bsum[bin] = bin total.
__global__ __launch_bounds__(1024) void k_scanT(int* __restrict__ hist,
                                                int* __restrict__ bsum) {
    __shared__ int ps[8][1024];
    int t = threadIdx.x, b0 = blockIdx.x * 8;
    int v[8];
#pragma unroll
    for (int j = 0; j < 8; ++j) {
        v[j] = (b0 + j < NB) ? hist[t * PAD + b0 + j] : 0;
        ps[j][t] = v[j];
    }
    __syncthreads();
    for (int off = 1; off < 1024; off <<= 1) {
        int u[8];
#pragma unroll
        for (int j = 0; j < 8; ++j) u[j] = (t >= off) ? ps[j][t - off] : 0;
        __syncthreads();
#pragma unroll
        for (int j = 0; j < 8; ++j) ps[j][t] += u[j];
        __syncthreads();
    }
#pragma unroll
    for (int j = 0; j < 8; ++j)
        if (b0 + j < NB) hist[t * PAD + b0 + j] = ps[j][t] - v[j];
    if (t == 1023) {
#pragma unroll
        for (int j = 0; j < 8; ++j)
            if (b0 + j < NB) bsum[b0 + j] = ps[j][t];
    }
}

// ---------- scatter: packed (src<<8 | dloc) into bin-contiguous ebuf ----------
__global__ __launch_bounds__(256) void k_scatter1(
    const int* __restrict__ src, const int* __restrict__ dst,
    const int* __restrict__ hist, const int* __restrict__ bsum,
    unsigned* __restrict__ ebuf)
{
    __shared__ int cur[NB];
    __shared__ int binoff_l[NB + 1];
    int t = threadIdx.x, blk = blockIdx.x;
    scan_bsum_wave0(bsum, binoff_l, t);
    __syncthreads();
    for (int i = t; i < NB; i += 256)
        cur[i] = binoff_l[i] + hist[blk * PAD + i];   // coalesced
    __syncthreads();
    for (int e = blk * 256 + t; e < NE; e += B1 * 256) {
        int d = dst[e];
        int p = atomicAdd(&cur[d >> BSH], 1);         // LDS atomic
        ebuf[p] = ((unsigned)src[e] << BSH) | (unsigned)(d & BMSK);
    }
}

// ---------- count: per-bin degrees -> dinv (needed by k_mm) ----------
__global__ __launch_bounds__(512) void k_count(const int* __restrict__ bsum,
                                               const unsigned* __restrict__ ebuf,
                                               float* __restrict__ dinv) {
    __shared__ int c[256];
    __shared__ int binoff_l[NB + 1];
    int t = threadIdx.x, b = blockIdx.x;
    scan_bsum_wave0(bsum, binoff_l, t);
    if (t < 256) c[t] = 0;
    __syncthreads();
    int e0 = binoff_l[b], e1 = binoff_l[b + 1];
    for (int e = e0 + t; e < e1; e += 512)
        atomicAdd(&c[ebuf[e] & BMSK], 1);
    __syncthreads();
    if (t < 256) {
        int node = (b << BSH) + t;
        if (node < NN) dinv[node] = rsqrtf((float)(c[t] + 1));
    }
}

// ---------- fused MFMA GEMMs: blocks [0,half): g = half(x@Wg * dinv)
//                              blocks [half,2*half): out = pos@Wp + bg + bp ----------
__global__ __launch_bounds__(256) void k_mm(
    const float* __restrict__ x, const float* __restrict__ Wg,
    const float* __restrict__ dinv, __half* __restrict__ g,
    const float* __restrict__ pos, const float* __restrict__ Wp,
    const float* __restrict__ bg, const float* __restrict__ bp,
    float* __restrict__ out)
{
    __shared__ __align__(16) _Float16 Wt[64][64];   // Wt[n][k] = W[k][n]
    int t = threadIdx.x;
    int lane = t & 63;
    int wid = t >> 6;
    int half_grid = gridDim.x >> 1;
    bool job2 = blockIdx.x >= half_grid;
    int blk = job2 ? (blockIdx.x - half_grid) : blockIdx.x;
    const float* A = job2 ? pos : x;
    const float* W = job2 ? Wp : Wg;

    // zero-pad row g[NN] (gather's invalid-edge target)
    if (blockIdx.x == 0 && t < 64) g[(long)NN * D + t] = __float2half(0.f);

    for (int i = t; i < 64 * 64; i += 256) {
        int k = i >> 6, n = i & 63;
        Wt[n][k] = (_Float16)W[i];
    }
    __syncthreads();

    int lr = lane & 15;        // A-row / C-col within tile
    int lg = lane >> 4;        // k-group / C-row-group
    int kofs = lg * 8;

    f16x8 b[4][2];             // hoisted B frags: [col-tile][k-tile]
#pragma unroll
    for (int n = 0; n < 4; ++n)
#pragma unroll
        for (int kt = 0; kt < 2; ++kt)
            b[n][kt] = *(const f16x8*)&Wt[n * 16 + lr][kt * 32 + kofs];

    float bsv[4] = {0.f, 0.f, 0.f, 0.f};
    if (job2) {
#pragma unroll
        for (int n = 0; n < 4; ++n) {
            int cc = n * 16 + lr;
            bsv[n] = bg[cc] + bp[cc];
        }
    }

    for (int rb0 = blk * 64; rb0 < NN; rb0 += half_grid * 64) {
        int rb = rb0 + wid * 16;
        int arow = rb + lr;
        int arc = arow < NN ? arow : NN - 1;
        const float4* ap = (const float4*)(A + (long)arc * 64 + kofs);
        float4 p0 = ap[0], p1 = ap[1], p2 = ap[8], p3 = ap[9];
        f16x8 a0, a1;
        a0[0] = (_Float16)p0.x; a0[1] = (_Float16)p0.y;
        a0[2] = (_Float16)p0.z; a0[3] = (_Float16)p0.w;
        a0[4] = (_Float16)p1.x; a0[5] = (_Float16)p1.y;
        a0[6] = (_Float16)p1.z; a0[7] = (_Float16)p1.w;
        a1[0] = (_Float16)p2.x; a1[1] = (_Float16)p2.y;
        a1[2] = (_Float16)p2.z; a1[3] = (_Float16)p2.w;
        a1[4] = (_Float16)p3.x; a1[5] = (_Float16)p3.y;
        a1[6] = (_Float16)p3.z; a1[7] = (_Float16)p3.w;

        f32x4 z = {0.f, 0.f, 0.f, 0.f};
        f32x4 acc[4] = {z, z, z, z};
#pragma unroll
        for (int n = 0; n < 4; ++n) {
            acc[n] = __builtin_amdgcn_mfma_f32_16x16x32_f16(a0, b[n][0], acc[n], 0, 0, 0);
            acc[n] = __builtin_amdgcn_mfma_f32_16x16x32_f16(a1, b[n][1], acc[n], 0, 0, 0);
        }

        int orow0 = rb + lg * 4;
        if (!job2) {
#pragma unroll
            for (int r = 0; r < 4; ++r) {
                int row = orow0 + r;
                if (row < NN) {
                    float di = dinv[row];
#pragma unroll
                    for (int n = 0; n < 4; ++n)
                        g[(long)row * D + n * 16 + lr] = __float2half(acc[n][r] * di);
                }
            }
        } else {
#pragma unroll
            for (int r = 0; r < 4; ++r) {
                int row = orow0 + r;
                if (row < NN) {
#pragma unroll
                    for (int n = 0; n < 4; ++n)
                        out[(long)row * D + n * 16 + lr] = acc[n][r] + bsv[n];
                }
            }
        }
    }
}

// ---------- fused sort + gather: one block per 256-node bin ----------
// phase1 stage+count -> phase2 wave-0 scan -> phase3 reg-staged in-place sort
// -> phase4 per-node gather with LDS bucket (broadcast ds_read, no shfl).
__global__ __launch_bounds__(1024) void k_gather(
    const int* __restrict__ bsum, unsigned* __restrict__ ebuf,
    const __half* __restrict__ g, float* __restrict__ out)
{
    __shared__ unsigned cache[CAPS];      // edges, then (in-place) sorted srcs
    __shared__ int c[256];                // degree counts (kept for dinv)
    __shared__ int cur[256];              // placement cursors
    __shared__ int rs_l[257];             // local row starts
    __shared__ int binoff_l[NB + 1];
    int t = threadIdx.x, b = blockIdx.x;
    int lane = t & 63, w = t >> 6;

    scan_bsum_wave0(bsum, binoff_l, t);
    if (t < 256) c[t] = 0;
    __syncthreads();
    int e0 = binoff_l[b];
    int cnt = binoff_l[b + 1] - e0;

    // phase 1: stage to LDS + count
    for (int i = t; i < cnt; i += 1024) {
        unsigned u = ebuf[e0 + i];
        if (i < CAPS) cache[i] = u;
        atomicAdd(&c[u & BMSK], 1);
    }
    __syncthreads();

    // phase 2: wave-0 scan of 256 counts
    if (t < 64) {
        int base = t * 4;
        int loc[4]; int run = 0;
#pragma unroll
        for (int j = 0; j < 4; ++j) { loc[j] = run; run += c[base + j]; }
        int pre = run;
#pragma unroll
        for (int off = 1; off < 64; off <<= 1) {
            int u = __shfl_up(pre, off);
            if (t >= off) pre += u;
        }
        pre -= run;
#pragma unroll
        for (int j = 0; j < 4; ++j) {
            rs_l[base + j] = pre + loc[j];
            cur[base + j]  = pre + loc[j];
        }
        if (t == 63) rs_l[256] = pre + run;   // == cnt
    }

    // phase 3a: stage all my edges into registers (before barrier)
    unsigned ur[8]; int nmy = 0;
    for (int i = t, j = 0; i < cnt && j < 8; i += 1024, ++j) {
        ur[j] = (i < CAPS) ? cache[i] : ebuf[e0 + i];
        nmy = j + 1;
    }
    __syncthreads();
    // phase 3b: place srcs (in-place into cache; overflow spills to ebuf)
    for (int j = 0; j < nmy; ++j) {
        unsigned u = ur[j];
        int p = atomicAdd(&cur[u & BMSK], 1);
        unsigned s = u >> BSH;
        if (p < CAPS) cache[p] = s; else ebuf[e0 + p] = s;
    }
    __syncthreads();

    // phase 4: per-node gather; wave w handles rows w, 16+w, ...
    int f = lane & 7;                 // 16B granule within 128B row
    int grp = lane >> 3;              // 8 edges per step
    const uint4* gq = (const uint4*)g;
    for (int p = 0; p < 16; ++p) {
        int r = p * 16 + w;
        int node = (b << BSH) + r;
        if (node >= NN) continue;
        int rs0 = rs_l[r];
        int nl = rs_l[r + 1] - rs0;
        float a0 = 0.f, a1 = 0.f, a2 = 0.f, a3 = 0.f;
        float a4 = 0.f, a5 = 0.f, a6 = 0.f, a7 = 0.f;
        int NG = (nl + 7) >> 3;
        for (int c2 = 0; c2 < NG; ++c2) {
            int idx = c2 * 8 + grp;
            int s = NN;
            if (idx < nl) {
                int ii = rs0 + idx;
                s = (ii < CAPS) ? (int)cache[ii] : (int)ebuf[e0 + ii];
            }
            uint4 u = gq[(long)s * 8 + f];
            __half2 h0 = *(__half2*)&u.x, h1 = *(__half2*)&u.y;
            __half2 h2 = *(__half2*)&u.z, h3 = *(__half2*)&u.w;
            a0 += __low2float(h0); a1 += __high2float(h0);
            a2 += __low2float(h1); a3 += __high2float(h1);
            a4 += __low2float(h2); a5 += __high2float(h2);
            a6 += __low2float(h3); a7 += __high2float(h3);
        }
#pragma unroll
        for (int mask = 8; mask <= 32; mask <<= 1) {
            a0 += __shfl_xor(a0, mask); a1 += __shfl_xor(a1, mask);
            a2 += __shfl_xor(a2, mask); a3 += __shfl_xor(a3, mask);
            a4 += __shfl_xor(a4, mask); a5 += __shfl_xor(a5, mask);
            a6 += __shfl_xor(a6, mask); a7 += __shfl_xor(a7, mask);
        }
        if (lane < 16) {
            int ff = lane & 7, hs = lane >> 3;
            uint4 u = gq[(long)node * 8 + ff];               // self row
            __half2 s0 = hs ? *(__half2*)&u.z : *(__half2*)&u.x;
            __half2 s1 = hs ? *(__half2*)&u.w : *(__half2*)&u.y;
            float b0 = hs ? a4 : a0, b1 = hs ? a5 : a1;
            float b2 = hs ? a6 : a2, b3 = hs ? a7 : a3;
            float di = rsqrtf((float)(c[r] + 1));
            float4* op = (float4*)(out + (long)node * D) + (ff * 2 + hs);
            float4 o = *op;
            o.x += (b0 + __low2float(s0)) * di;
            o.y += (b1 + __high2float(s0)) * di;
            o.z += (b2 + __low2float(s1)) * di;
            o.w += (b3 + __high2float(s1)) * di;
            *op = o;
        }
    }
}

extern "C" void kernel_launch(void* const* d_in, const int* in_sizes, int n_in,
                              void* d_out, int out_size, void* d_ws, size_t ws_size,
                              hipStream_t stream) {
    const float* x   = (const float*)d_in[0];
    const int*   ei  = (const int*)d_in[1];   // [2, NE] int32
    const float* pos = (const float*)d_in[2];
    const float* Wg  = (const float*)d_in[3];
    const float* bg  = (const float*)d_in[4];
    const float* Wp  = (const float*)d_in[5];
    const float* bp  = (const float*)d_in[6];
    float* out = (float*)d_out;

    const int* src = ei;
    const int* dst = ei + NE;

    // ws layout (~21.2 MiB):
    //   [0)          ebuf[NE] u32
    //   [6,400,000)  g[(NN+1)*D] half  (128B-aligned rows; row NN = zeros)
    //   [19,200,128) hist[B1*PAD] | bsum[512] | dinv[NN]
    char* Wb = (char*)d_ws;
    unsigned* ebuf = (unsigned*)Wb;
    __half*   g    = (__half*)(Wb + 6400000);
    int*      hist = (int*)(Wb + 19200128);
    int*      bsum = hist + B1 * PAD;
    float*    dinv = (float*)(bsum + 512);

    hipLaunchKernelGGL(k_hist,     dim3(B1),   dim3(256),  0, stream, dst, hist);
    hipLaunchKernelGGL(k_scanT,    dim3(49),   dim3(1024), 0, stream, hist, bsum);
    hipLaunchKernelGGL(k_scatter1, dim3(B1),   dim3(256),  0, stream,
                       src, dst, hist, bsum, ebuf);
    hipLaunchKernelGGL(k_count,    dim3(NB),   dim3(512),  0, stream,
                       bsum, ebuf, dinv);
    hipLaunchKernelGGL(k_mm,       dim3(1564), dim3(256),  0, stream,
                       x, Wg, dinv, g, pos, Wp, bg, bp, out);
    hipLaunchKernelGGL(k_gather,   dim3(NB),   dim3(1024), 0, stream,
                       bsum, ebuf, g, out);
}

// Round 8
// 207.599 us; speedup vs baseline: 1.0653x; 1.0653x over previous
//
#include <hip/hip_runtime.h>
#include <hip/hip_fp16.h>

#define NN 100000
#define NE 1600000
#define D  64

#define SB    256        // hist/scatter blocks
#define CHUNK 6250       // NE / SB
#define BSH   7          // bin = dst >> 7  (128 nodes per bin)
#define BMSK  127
#define NB    782        // ceil(NN / 128)
#define PAD   784        // hist row stride (ints)
#define CAPS  2560       // LDS edge capacity per bin (mean 2046, ~11 sigma)

typedef __attribute__((ext_vector_type(8))) _Float16 f16x8;
typedef __attribute__((ext_vector_type(4))) float    f32x4;

// wave-0 helper: exclusive scan of bsum[0..NB) -> binoff_l[0..NB]
__device__ __forceinline__ void scan_bsum_wave0(const int* __restrict__ bsum,
                                                int* binoff_l, int t) {
    if (t < 64) {
        int base = t * 13;                   // 64*13 = 832 >= 783
        int loc[13]; int run = 0;
#pragma unroll
        for (int j = 0; j < 13; ++j) {
            int idx = base + j;
            int v = (idx < NB) ? bsum[idx] : 0;
            loc[j] = run; run += v;
        }
        int pre = run;
#pragma unroll
        for (int off = 1; off < 64; off <<= 1) {
            int u = __shfl_up(pre, off);
            if (t >= off) pre += u;
        }
        pre -= run;                          // exclusive over lanes
#pragma unroll
        for (int j = 0; j < 13; ++j) {
            int idx = base + j;
            if (idx <= NB) binoff_l[idx] = pre + loc[j];
        }
    }
}

// ---------- hist: per-block bin counts, block-major (coalesced) ----------
__global__ __launch_bounds__(1024) void k_hist(const int* __restrict__ dst,
                                               int* __restrict__ hist) {
    __shared__ int h[NB];
    int t = threadIdx.x, blk = blockIdx.x;
    for (int i = t; i < NB; i += 1024) h[i] = 0;
    __syncthreads();
    int e0 = blk * CHUNK;
    for (int e = e0 + t; e < e0 + CHUNK; e += 1024)
        atomicAdd(&h[dst[e] >> BSH], 1);
    __syncthreads();
    for (int i = t; i < NB; i += 1024) hist[blk * PAD + i] = h[i];
}

// ---------- scanT: per-bin exclusive scan over the 256 block counts ----------
// 8 bins per block; hist updated in-place; bsum[bin] = bin total.
__global__ __launch_bounds__(256) void k_scanT(int* __restrict__ hist,
                                               int* __restrict__ bsum) {
    __shared__ int ps[8][256];
    int t = threadIdx.x, b0 = blockIdx.x * 8;
    int v[8];
#pragma unroll
    for (int j = 0; j < 8; ++j) {
        v[j] = (b0 + j < NB) ? hist[t * PAD + b0 + j] : 0;
        ps[j][t] = v[j];
    }
    __syncthreads();
    for (int off = 1; off < 256; off <<= 1) {
        int u[8];
#pragma unroll
        for (int j = 0; j < 8; ++j) u[j] = (t >= off) ? ps[j][t - off] : 0;
        __syncthreads();
#pragma unroll
        for (int j = 0; j < 8; ++j) ps[j][t] += u[j];
        __syncthreads();
    }
#pragma unroll
    for (int j = 0; j < 8; ++j)
        if (b0 + j < NB) hist[t * PAD + b0 + j] = ps[j][t] - v[j];
    if (t == 255) {
#pragma unroll
        for (int j = 0; j < 8; ++j)
            if (b0 + j < NB) bsum[b0 + j] = ps[j][t];
    }
}

// ---------- scatter: packed (src<<7 | dloc) into bin-contiguous ebuf ----------
// 256 blocks: each block's per-bin run ~8 edges (32B) -> private L2 lines.
__global__ __launch_bounds__(1024) void k_scatter1(
    const int* __restrict__ src, const int* __restrict__ dst,
    const int* __restrict__ hist, const int* __restrict__ bsum,
    unsigned* __restrict__ ebuf)
{
    __shared__ int cur[NB];
    __shared__ int binoff_l[NB + 1];
    int t = threadIdx.x, blk = blockIdx.x;
    scan_bsum_wave0(bsum, binoff_l, t);
    __syncthreads();
    for (int i = t; i < NB; i += 1024)
        cur[i] = binoff_l[i] + hist[blk * PAD + i];   // coalesced
    __syncthreads();
    int e0 = blk * CHUNK;
    for (int e = e0 + t; e < e0 + CHUNK; e += 1024) {
        int d = dst[e];
        int p = atomicAdd(&cur[d >> BSH], 1);         // LDS atomic
        ebuf[p] = ((unsigned)src[e] << BSH) | (unsigned)(d & BMSK);
    }
}

// ---------- count: per-bin degrees -> dinv (needed by k_mm) ----------
__global__ __launch_bounds__(512) void k_count(const int* __restrict__ bsum,
                                               const unsigned* __restrict__ ebuf,
                                               float* __restrict__ dinv) {
    __shared__ int c[128];
    __shared__ int binoff_l[NB + 1];
    int t = threadIdx.x, b = blockIdx.x;
    scan_bsum_wave0(bsum, binoff_l, t);
    if (t < 128) c[t] = 0;
    __syncthreads();
    int e0 = binoff_l[b], e1 = binoff_l[b + 1];
    for (int e = e0 + t; e < e1; e += 512)
        atomicAdd(&c[ebuf[e] & BMSK], 1);
    __syncthreads();
    if (t < 128) {
        int node = (b << BSH) + t;
        if (node < NN) dinv[node] = rsqrtf((float)(c[t] + 1));
    }
}

// ---------- fused MFMA GEMMs: blocks [0,half): g = half(x@Wg * dinv)
//                              blocks [half,2*half): out = pos@Wp + bg + bp ----------
__global__ __launch_bounds__(256) void k_mm(
    const float* __restrict__ x, const float* __restrict__ Wg,
    const float* __restrict__ dinv, __half* __restrict__ g,
    const float* __restrict__ pos, const float* __restrict__ Wp,
    const float* __restrict__ bg, const float* __restrict__ bp,
    float* __restrict__ out)
{
    __shared__ __align__(16) _Float16 Wt[64][64];   // Wt[n][k] = W[k][n]
    int t = threadIdx.x;
    int lane = t & 63;
    int wid = t >> 6;
    int half_grid = gridDim.x >> 1;
    bool job2 = blockIdx.x >= half_grid;
    int blk = job2 ? (blockIdx.x - half_grid) : blockIdx.x;
    const float* A = job2 ? pos : x;
    const float* W = job2 ? Wp : Wg;

    // zero-pad row g[NN] (gather's invalid-edge target)
    if (blockIdx.x == 0 && t < 64) g[(long)NN * D + t] = __float2half(0.f);

    for (int i = t; i < 64 * 64; i += 256) {
        int k = i >> 6, n = i & 63;
        Wt[n][k] = (_Float16)W[i];
    }
    __syncthreads();

    int lr = lane & 15;        // A-row / C-col within tile
    int lg = lane >> 4;        // k-group / C-row-group
    int kofs = lg * 8;

    f16x8 b[4][2];             // hoisted B frags: [col-tile][k-tile]
#pragma unroll
    for (int n = 0; n < 4; ++n)
#pragma unroll
        for (int kt = 0; kt < 2; ++kt)
            b[n][kt] = *(const f16x8*)&Wt[n * 16 + lr][kt * 32 + kofs];

    float bsv[4] = {0.f, 0.f, 0.f, 0.f};
    if (job2) {
#pragma unroll
        for (int n = 0; n < 4; ++n) {
            int cc = n * 16 + lr;
            bsv[n] = bg[cc] + bp[cc];
        }
    }

    for (int rb0 = blk * 64; rb0 < NN; rb0 += half_grid * 64) {
        int rb = rb0 + wid * 16;
        int arow = rb + lr;
        int arc = arow < NN ? arow : NN - 1;
        const float4* ap = (const float4*)(A + (long)arc * 64 + kofs);
        float4 p0 = ap[0], p1 = ap[1], p2 = ap[8], p3 = ap[9];
        f16x8 a0, a1;
        a0[0] = (_Float16)p0.x; a0[1] = (_Float16)p0.y;
        a0[2] = (_Float16)p0.z; a0[3] = (_Float16)p0.w;
        a0[4] = (_Float16)p1.x; a0[5] = (_Float16)p1.y;
        a0[6] = (_Float16)p1.z; a0[7] = (_Float16)p1.w;
        a1[0] = (_Float16)p2.x; a1[1] = (_Float16)p2.y;
        a1[2] = (_Float16)p2.z; a1[3] = (_Float16)p2.w;
        a1[4] = (_Float16)p3.x; a1[5] = (_Float16)p3.y;
        a1[6] = (_Float16)p3.z; a1[7] = (_Float16)p3.w;

        f32x4 z = {0.f, 0.f, 0.f, 0.f};
        f32x4 acc[4] = {z, z, z, z};
#pragma unroll
        for (int n = 0; n < 4; ++n) {
            acc[n] = __builtin_amdgcn_mfma_f32_16x16x32_f16(a0, b[n][0], acc[n], 0, 0, 0);
            acc[n] = __builtin_amdgcn_mfma_f32_16x16x32_f16(a1, b[n][1], acc[n], 0, 0, 0);
        }

        int orow0 = rb + lg * 4;
        if (!job2) {
#pragma unroll
            for (int r = 0; r < 4; ++r) {
                int row = orow0 + r;
                if (row < NN) {
                    float di = dinv[row];
#pragma unroll
                    for (int n = 0; n < 4; ++n)
                        g[(long)row * D + n * 16 + lr] = __float2half(acc[n][r] * di);
                }
            }
        } else {
#pragma unroll
            for (int r = 0; r < 4; ++r) {
                int row = orow0 + r;
                if (row < NN) {
#pragma unroll
                    for (int n = 0; n < 4; ++n)
                        out[(long)row * D + n * 16 + lr] = acc[n][r] + bsv[n];
                }
            }
        }
    }
}

// ---------- fused sort + gather: one block (512 thr) per 128-node bin ----------
__global__ __launch_bounds__(512) void k_gather(
    const int* __restrict__ bsum, unsigned* __restrict__ ebuf,
    const __half* __restrict__ g, float* __restrict__ out)
{
    __shared__ unsigned cache[CAPS];      // edges, then (in-place) sorted srcs
    __shared__ int c[128];                // degree counts (kept for dinv)
    __shared__ int cur[128];              // placement cursors
    __shared__ int rs_l[129];             // local row starts
    __shared__ int binoff_l[NB + 1];
    int t = threadIdx.x, b = blockIdx.x;
    int lane = t & 63, w = t >> 6;        // 8 waves

    scan_bsum_wave0(bsum, binoff_l, t);
    if (t < 128) c[t] = 0;
    __syncthreads();
    int e0 = binoff_l[b];
    int cnt = binoff_l[b + 1] - e0;

    // phase 1: stage to LDS + count
    for (int i = t; i < cnt; i += 512) {
        unsigned u = ebuf[e0 + i];
        if (i < CAPS) cache[i] = u;
        atomicAdd(&c[u & BMSK], 1);
    }
    __syncthreads();

    // phase 2: wave-0 scan of 128 counts
    if (t < 64) {
        int l0 = c[2 * t], l1 = c[2 * t + 1];
        int run = l0 + l1;
        int pre = run;
#pragma unroll
        for (int off = 1; off < 64; off <<= 1) {
            int u = __shfl_up(pre, off);
            if (t >= off) pre += u;
        }
        pre -= run;
        rs_l[2 * t] = pre;        cur[2 * t] = pre;
        rs_l[2 * t + 1] = pre + l0; cur[2 * t + 1] = pre + l0;
        if (t == 63) rs_l[128] = pre + run;   // == cnt
    }

    // phase 3a: stage all my edges into registers (before barrier)
    unsigned ur[8]; int nmy = 0;
    for (int i = t, j = 0; i < cnt && j < 8; i += 512, ++j) {
        ur[j] = (i < CAPS) ? cache[i] : ebuf[e0 + i];
        nmy = j + 1;
    }
    __syncthreads();
    // phase 3b: place srcs (in-place into cache; overflow spills to ebuf)
    for (int j = 0; j < nmy; ++j) {
        unsigned u = ur[j];
        int p = atomicAdd(&cur[u & BMSK], 1);
        unsigned s = u >> BSH;
        if (p < CAPS) cache[p] = s; else ebuf[e0 + p] = s;
    }
    __syncthreads();

    // phase 4: per-node gather; wave w handles rows w, 8+w, ...
    int f = lane & 7;                 // 16B granule within 128B row
    int grp = lane >> 3;              // 8 edges per step
    const uint4* gq = (const uint4*)g;
    for (int p = 0; p < 16; ++p) {
        int r = p * 8 + w;
        int node = (b << BSH) + r;
        if (node >= NN) continue;
        int rs0 = rs_l[r];
        int nl = rs_l[r + 1] - rs0;
        float a0 = 0.f, a1 = 0.f, a2 = 0.f, a3 = 0.f;
        float a4 = 0.f, a5 = 0.f, a6 = 0.f, a7 = 0.f;
        int NG = (nl + 7) >> 3;
        for (int c2 = 0; c2 < NG; ++c2) {
            int idx = c2 * 8 + grp;
            int s = NN;
            if (idx < nl) {
                int ii = rs0 + idx;
                s = (ii < CAPS) ? (int)cache[ii] : (int)ebuf[e0 + ii];
            }
            uint4 u = gq[(long)s * 8 + f];
            __half2 h0 = *(__half2*)&u.x, h1 = *(__half2*)&u.y;
            __half2 h2 = *(__half2*)&u.z, h3 = *(__half2*)&u.w;
            a0 += __low2float(h0); a1 += __high2float(h0);
            a2 += __low2float(h1); a3 += __high2float(h1);
            a4 += __low2float(h2); a5 += __high2float(h2);
            a6 += __low2float(h3); a7 += __high2float(h3);
        }
#pragma unroll
        for (int mask = 8; mask <= 32; mask <<= 1) {
            a0 += __shfl_xor(a0, mask); a1 += __shfl_xor(a1, mask);
            a2 += __shfl_xor(a2, mask); a3 += __shfl_xor(a3, mask);
            a4 += __shfl_xor(a4, mask); a5 += __shfl_xor(a5, mask);
            a6 += __shfl_xor(a6, mask); a7 += __shfl_xor(a7, mask);
        }
        if (lane < 16) {
            int ff = lane & 7, hs = lane >> 3;
            uint4 u = gq[(long)node * 8 + ff];               // self row
            __half2 s0 = hs ? *(__half2*)&u.z : *(__half2*)&u.x;
            __half2 s1 = hs ? *(__half2*)&u.w : *(__half2*)&u.y;
            float b0 = hs ? a4 : a0, b1 = hs ? a5 : a1;
            float b2 = hs ? a6 : a2, b3 = hs ? a7 : a3;
            float di = rsqrtf((float)(c[r] + 1));
            float4* op = (float4*)(out + (long)node * D) + (ff * 2 + hs);
            float4 o = *op;
            o.x += (b0 + __low2float(s0)) * di;
            o.y += (b1 + __high2float(s0)) * di;
            o.z += (b2 + __low2float(s1)) * di;
            o.w += (b3 + __high2float(s1)) * di;
            *op = o;
        }
    }
}

extern "C" void kernel_launch(void* const* d_in, const int* in_sizes, int n_in,
                              void* d_out, int out_size, void* d_ws, size_t ws_size,
                              hipStream_t stream) {
    const float* x   = (const float*)d_in[0];
    const int*   ei  = (const int*)d_in[1];   // [2, NE] int32
    const float* pos = (const float*)d_in[2];
    const float* Wg  = (const float*)d_in[3];
    const float* bg  = (const float*)d_in[4];
    const float* Wp  = (const float*)d_in[5];
    const float* bp  = (const float*)d_in[6];
    float* out = (float*)d_out;

    const int* src = ei;
    const int* dst = ei + NE;

    // ws layout (~20.4 MiB):
    //   [0)          ebuf[NE] u32
    //   [6,400,000)  g[(NN+1)*D] half  (128B-aligned rows; row NN = zeros)
    //   [19,200,128) hist[SB*PAD] | bsum[784] | dinv[NN]
    char* Wb = (char*)d_ws;
    unsigned* ebuf = (unsigned*)Wb;
    __half*   g    = (__half*)(Wb + 6400000);
    int*      hist = (int*)(Wb + 19200128);
    int*      bsum = hist + SB * PAD;
    float*    dinv = (float*)(bsum + 784);

    hipLaunchKernelGGL(k_hist,     dim3(SB),   dim3(1024), 0, stream, dst, hist);
    hipLaunchKernelGGL(k_scanT,    dim3(98),   dim3(256),  0, stream, hist, bsum);
    hipLaunchKernelGGL(k_scatter1, dim3(SB),   dim3(1024), 0, stream,
                       src, dst, hist, bsum, ebuf);
    hipLaunchKernelGGL(k_count,    dim3(NB),   dim3(512),  0, stream,
                       bsum, ebuf, dinv);
    hipLaunchKernelGGL(k_mm,       dim3(1564), dim3(256),  0, stream,
                       x, Wg, dinv, g, pos, Wp, bg, bp, out);
    hipLaunchKernelGGL(k_gather,   dim3(NB),   dim3(512),  0, stream,
                       bsum, ebuf, g, out);
}